// Round 1
// baseline (674.277 us; speedup 1.0000x reference)
//
#include <hip/hip_runtime.h>
#include <stdint.h>

// Problem constants (B=8, S=8192, D_IN=512, D=512)
#define Bb   8
#define Ss   8192
#define DIN  512
#define Dd   512
#define M_TOT (Bb * Ss)      // 65536 rows
#define NC   64              // chunks along S
#define CL   128             // chunk length (NC*CL == Ss)

// ws layout (bytes)
static const size_t CV_OFF  = 0;                          // float2[65536][512] = 256 MiB
static const size_t XS_OFF  = 268435456ull;               // bf16 [65536][1024] = 128 MiB (hi | lo)
static const size_t WT_OFF  = XS_OFF + 134217728ull;      // bf16 [1024][1536]  = 3 MiB
static const size_t AG_OFF  = WT_OFF + 3145728ull;        // float2[8][64][512] = 2 MiB
static const size_t HIN_OFF = AG_OFF + 2097152ull;        // float [8][64][512] = 1 MiB
static const size_t WS_NEED = HIN_OFF + 1048576ull;       // ~390 MiB total

typedef short  short8 __attribute__((ext_vector_type(8)));
typedef float  f32x4  __attribute__((ext_vector_type(4)));

__device__ __forceinline__ unsigned short bf16_rne(float f) {
  uint32_t u = __float_as_uint(f);
  u += 0x7fffu + ((u >> 16) & 1u);
  return (unsigned short)(u >> 16);
}
__device__ __forceinline__ float bf16f(unsigned short h) {
  return __uint_as_float(((uint32_t)h) << 16);
}

__device__ __forceinline__ void gload16(const unsigned short* g, void* l) {
  __builtin_amdgcn_global_load_lds(
      (const __attribute__((address_space(1))) uint32_t*)g,
      (__attribute__((address_space(3))) uint32_t*)l, 16, 0, 0);
}

// ---------------------------------------------------------------------------
// Pre-pass 1: x (f32) -> xs bf16 [row][0:512)=hi, [512:1024)=lo
// ---------------------------------------------------------------------------
__global__ void k_convert_x(const float* __restrict__ x, unsigned short* __restrict__ xs) {
  const size_t n4 = (size_t)M_TOT * DIN / 4;
  for (size_t i = (size_t)blockIdx.x * blockDim.x + threadIdx.x; i < n4;
       i += (size_t)gridDim.x * blockDim.x) {
    float4 v = ((const float4*)x)[i];
    size_t e = i * 4;
    size_t r = e >> 9;            // row (0..65535)
    int    k = (int)(e & 511);    // col in [0,512), multiple of 4
    float f[4] = {v.x, v.y, v.z, v.w};
    ushort4 hi, lo;
    unsigned short* hp = (unsigned short*)&hi;
    unsigned short* lp = (unsigned short*)&lo;
#pragma unroll
    for (int j = 0; j < 4; ++j) {
      unsigned short h = bf16_rne(f[j]);
      hp[j] = h;
      lp[j] = bf16_rne(f[j] - bf16f(h));
    }
    *(ushort4*)(xs + r * 1024 + k)       = hi;
    *(ushort4*)(xs + r * 1024 + 512 + k) = lo;
  }
}

// ---------------------------------------------------------------------------
// Pre-pass 2: build Wt bf16 [1024 n'][1536 k]
//   n' column interleave (16-granular): group t = n'>>5, u = n'&31
//     u<16  -> hidden col  d = 16t + u        (W col d)
//     u>=16 -> gate   col  d = 16t + (u-16)   (W col 512+d)
//   k segments: [0,512)=Wh, [512,1024)=Wh, [1024,1536)=Wl  (pairs A = [xh|xl|xh])
// ---------------------------------------------------------------------------
__global__ void k_build_wt(const float* __restrict__ W, unsigned short* __restrict__ wt) {
  const int total = 1024 * 1536;
  for (int i = blockIdx.x * blockDim.x + threadIdx.x; i < total;
       i += gridDim.x * blockDim.x) {
    int n = i / 1536;
    int k = i - n * 1536;
    int t = n >> 5, u = n & 31;
    int j = 16 * t + (u & 15) + ((u & 16) ? 512 : 0);
    int ks = k & 511;
    float w = W[(size_t)ks * 1024 + j];
    unsigned short hi = bf16_rne(w);
    unsigned short val;
    if (k < 1024) val = hi;
    else          val = bf16_rne(w - bf16f(hi));
    wt[i] = val;
  }
}

// ---------------------------------------------------------------------------
// GEMM: (65536 x 1536_eff) * (1536 x 1024) -> fused pointwise -> cv float2
// m97-style: 128x128 tile, BK=32, 4 waves (2x2 of 64x64), 16x16x32 bf16 MFMA,
// global_load_lds width 16, 2 barriers per K-step.
// ---------------------------------------------------------------------------
__global__ void __launch_bounds__(256) k_gemm(const unsigned short* __restrict__ xs,
                                              const unsigned short* __restrict__ wt,
                                              float2* __restrict__ cv) {
  __shared__ __align__(16) unsigned short As[128 * 32];
  __shared__ __align__(16) unsigned short Bs[128 * 32];
  const int tid  = threadIdx.x;
  const int lane = tid & 63;
  const int wave = tid >> 6;
  const int wr = wave >> 1, wc = wave & 1;
  const int bid = blockIdx.x;
  const int nb = bid >> 9;       // 0..7   (consecutive bids share the B panel)
  const int mb = bid & 511;      // 0..511
  const int m0 = mb * 128, n0 = nb * 128;

  f32x4 acc[4][4] = {};

  // staging: t = tid (+256); row = t>>2 (0..63, +64), kchunk = t&3
  const int trow = tid >> 2;
  const int tk   = 8 * (tid & 3);
  const size_t aoff0 = (size_t)(m0 + trow) * 1024 + tk;
  const size_t aoff1 = aoff0 + (size_t)64 * 1024;
  const size_t boff0 = (size_t)(n0 + trow) * 1536 + tk;
  const size_t boff1 = boff0 + (size_t)64 * 1536;

  char* ldsA = (char*)As + wave * 1024;   // wave-uniform LDS base (+ lane*16 by HW)
  char* ldsB = (char*)Bs + wave * 1024;

  const int ra = (lane & 15) * 32 + 8 * (lane >> 4);  // frag element offset within tile

  for (int kt = 0; kt < 48; ++kt) {
    const int k0 = kt * 32;
    const int ka = (k0 < 1024) ? k0 : (k0 - 1024);  // A k-source: [xh | xl | xh]
    __syncthreads();
    gload16(xs + aoff0 + ka, ldsA);
    gload16(xs + aoff1 + ka, ldsA + 4096);
    gload16(wt + boff0 + k0, ldsB);
    gload16(wt + boff1 + k0, ldsB + 4096);
    __syncthreads();
    short8 af[4], bfr[4];
#pragma unroll
    for (int m = 0; m < 4; ++m)
      af[m] = *(const short8*)(As + (wr * 64 + 16 * m) * 32 + ra);
#pragma unroll
    for (int n = 0; n < 4; ++n)
      bfr[n] = *(const short8*)(Bs + (wc * 64 + 16 * n) * 32 + ra);
#pragma unroll
    for (int m = 0; m < 4; ++m)
#pragma unroll
      for (int n = 0; n < 4; ++n)
        acc[m][n] = __builtin_amdgcn_mfma_f32_16x16x32_bf16(af[m], bfr[n], acc[m][n], 0, 0, 0);
  }

  // Epilogue: acc[m][2t] = hidden, acc[m][2t+1] = gate for the SAME d (same lane).
  // D layout: col = lane&15, row = (lane>>4)*4 + j  [measured m89]
  const int rbase = m0 + wr * 64 + ((lane >> 4) << 2);
  const int dbase = nb * 64 + wc * 32 + (lane & 15);
#pragma unroll
  for (int m = 0; m < 4; ++m) {
#pragma unroll
    for (int t = 0; t < 2; ++t) {
#pragma unroll
      for (int j = 0; j < 4; ++j) {
        float hid = acc[m][2 * t][j];
        float gat = acc[m][2 * t + 1][j];
        float eg = __expf(gat);
        float c  = 1.f / (1.f + eg);     // sigmoid(-gate) = exp(-softplus(gate))
        float z  = 1.f - c;              // sigmoid(gate), NaN-safe at gate=+inf
        float gv = (hid >= 0.f) ? (hid + 0.5f) : (1.f / (1.f + __expf(-hid)));
        int R = rbase + 16 * m + j;
        int d = dbase + 16 * t;
        cv[(size_t)R * 512 + d] = make_float2(c, z * gv);
      }
    }
  }
}

// ---------------------------------------------------------------------------
// Scan kernel A: per-chunk aggregates (C = prod c, V = local scan from 0)
// ---------------------------------------------------------------------------
__global__ void k_scan_chunk(const float2* __restrict__ cv, float2* __restrict__ agg) {
  const int bid = blockIdx.x;
  const int dh = bid & 1;
  const int chunk = (bid >> 1) & 63;
  const int b = bid >> 7;
  const int d = dh * 256 + threadIdx.x;
  size_t base = ((size_t)(b * Ss + chunk * CL)) * 512 + d;
  float C = 1.f, V = 0.f;
#pragma unroll 4
  for (int i = 0; i < CL; ++i) {
    float2 t = cv[base + (size_t)i * 512];
    V = fmaf(t.x, V, t.y);
    C *= t.x;
  }
  agg[((size_t)(b * NC + chunk)) * 512 + d] = make_float2(C, V);
}

// ---------------------------------------------------------------------------
// Scan kernel B: chain the 64 chunk aggregates per (b,d); h0 = g(prev_hidden)
// ---------------------------------------------------------------------------
__global__ void k_chain(const float* __restrict__ prev, const float2* __restrict__ agg,
                        float* __restrict__ hin) {
  const int b = blockIdx.x;
  const int d = threadIdx.x;  // 512 threads
  float p = prev[b * 512 + d];
  float h = (p >= 0.f) ? (p + 0.5f) : (1.f / (1.f + __expf(-p)));
  for (int k = 0; k < NC; ++k) {
    size_t idx = ((size_t)(b * NC + k)) * 512 + d;
    hin[idx] = h;
    float2 a = agg[idx];
    h = fmaf(a.x, h, a.y);
  }
}

// ---------------------------------------------------------------------------
// Scan kernel C: replay chunks with correct incoming h, write output
// ---------------------------------------------------------------------------
__global__ void k_scan_out(const float2* __restrict__ cv, const float* __restrict__ hin,
                           float* __restrict__ out) {
  const int bid = blockIdx.x;
  const int dh = bid & 1;
  const int chunk = (bid >> 1) & 63;
  const int b = bid >> 7;
  const int d = dh * 256 + threadIdx.x;
  float h = hin[((size_t)(b * NC + chunk)) * 512 + d];
  size_t base = ((size_t)(b * Ss + chunk * CL)) * 512 + d;
#pragma unroll 4
  for (int i = 0; i < CL; ++i) {
    float2 t = cv[base + (size_t)i * 512];
    h = fmaf(t.x, h, t.y);
    out[base + (size_t)i * 512] = h;
  }
}

// ---------------------------------------------------------------------------
extern "C" void kernel_launch(void* const* d_in, const int* in_sizes, int n_in,
                              void* d_out, int out_size, void* d_ws, size_t ws_size,
                              hipStream_t stream) {
  if (ws_size < WS_NEED) return;  // need ~390 MiB scratch

  const float* x    = (const float*)d_in[0];
  const float* prev = (const float*)d_in[1];
  const float* W    = (const float*)d_in[2];
  float* out = (float*)d_out;
  char* ws = (char*)d_ws;

  float2*         cv  = (float2*)(ws + CV_OFF);
  unsigned short* xs  = (unsigned short*)(ws + XS_OFF);
  unsigned short* wt  = (unsigned short*)(ws + WT_OFF);
  float2*         agg = (float2*)(ws + AG_OFF);
  float*          hin = (float*)(ws + HIN_OFF);

  k_convert_x<<<dim3(4096), dim3(256), 0, stream>>>(x, xs);
  k_build_wt<<<dim3(512), dim3(256), 0, stream>>>(W, wt);
  k_gemm<<<dim3(4096), dim3(256), 0, stream>>>(xs, wt, cv);
  k_scan_chunk<<<dim3(1024), dim3(256), 0, stream>>>(cv, agg);
  k_chain<<<dim3(8), dim3(512), 0, stream>>>(prev, agg, hin);
  k_scan_out<<<dim3(1024), dim3(256), 0, stream>>>(cv, hin, out);
}

// Round 2
// 541.167 us; speedup vs baseline: 1.2460x; 1.2460x over previous
//
#include <hip/hip_runtime.h>
#include <stdint.h>

// Problem constants (B=8, S=8192, D_IN=512, D=512)
#define Bb   8
#define Ss   8192
#define DIN  512
#define Dd   512
#define M_TOT (Bb * Ss)      // 65536 rows
#define NC   64              // chunks along S
#define CL   128             // chunk length (NC*CL == Ss) == GEMM M-tile

// ws layout (bytes)
static const size_t CV_OFF  = 0;                          // float2[65536][512] = 256 MiB
static const size_t XS_OFF  = 268435456ull;               // bf16 [65536][1024] = 128 MiB (hi | lo)
static const size_t WT_OFF  = XS_OFF + 134217728ull;      // bf16 [1024][1024]  = 2 MiB
static const size_t AG_OFF  = WT_OFF + 3145728ull;        // float2[8][64][512] = 2 MiB
static const size_t HIN_OFF = AG_OFF + 2097152ull;        // float [8][64][512] = 1 MiB
static const size_t WS_NEED = HIN_OFF + 1048576ull;       // ~390 MiB total

typedef short  short8 __attribute__((ext_vector_type(8)));
typedef float  f32x4  __attribute__((ext_vector_type(4)));

__device__ __forceinline__ unsigned short bf16_rne(float f) {
  uint32_t u = __float_as_uint(f);
  u += 0x7fffu + ((u >> 16) & 1u);
  return (unsigned short)(u >> 16);
}
__device__ __forceinline__ float bf16f(unsigned short h) {
  return __uint_as_float(((uint32_t)h) << 16);
}

__device__ __forceinline__ void gload16(const unsigned short* g, void* l) {
  __builtin_amdgcn_global_load_lds(
      (const __attribute__((address_space(1))) uint32_t*)g,
      (__attribute__((address_space(3))) uint32_t*)l, 16, 0, 0);
}

// ---------------------------------------------------------------------------
// Pre-pass 1: x (f32) -> xs bf16 [row][0:512)=hi, [512:1024)=lo
// ---------------------------------------------------------------------------
__global__ void k_convert_x(const float* __restrict__ x, unsigned short* __restrict__ xs) {
  const size_t n4 = (size_t)M_TOT * DIN / 4;
  for (size_t i = (size_t)blockIdx.x * blockDim.x + threadIdx.x; i < n4;
       i += (size_t)gridDim.x * blockDim.x) {
    float4 v = ((const float4*)x)[i];
    size_t e = i * 4;
    size_t r = e >> 9;            // row (0..65535)
    int    k = (int)(e & 511);    // col in [0,512), multiple of 4
    float f[4] = {v.x, v.y, v.z, v.w};
    ushort4 hi, lo;
    unsigned short* hp = (unsigned short*)&hi;
    unsigned short* lp = (unsigned short*)&lo;
#pragma unroll
    for (int j = 0; j < 4; ++j) {
      unsigned short h = bf16_rne(f[j]);
      hp[j] = h;
      lp[j] = bf16_rne(f[j] - bf16f(h));
    }
    *(ushort4*)(xs + r * 1024 + k)       = hi;
    *(ushort4*)(xs + r * 1024 + 512 + k) = lo;
  }
}

// ---------------------------------------------------------------------------
// Pre-pass 2: build Wt bf16 [1024 n'][1024 k]  (B = [Wh | Wh], k dup at 512)
//   n' column interleave (16-granular): t = n'>>5, u = n'&31
//     u<16  -> hidden col  d = 16t + u        (W col d)
//     u>=16 -> gate   col  d = 16t + (u-16)   (W col 512+d)
// ---------------------------------------------------------------------------
__global__ void k_build_wt(const float* __restrict__ W, unsigned short* __restrict__ wt) {
  const int total = 1024 * 1024;
  for (int i = blockIdx.x * blockDim.x + threadIdx.x; i < total;
       i += gridDim.x * blockDim.x) {
    int n = i >> 10;
    int k = i & 1023;
    int t = n >> 5, u = n & 31;
    int j = 16 * t + (u & 15) + ((u & 16) ? 512 : 0);
    int ks = k & 511;
    wt[i] = bf16_rne(W[(size_t)ks * 1024 + j]);
  }
}

// ---------------------------------------------------------------------------
// GEMM: (65536 x 1024_eff) * (1024 x 1024) -> fused pointwise -> cv float2
//       + fused per-chunk scan aggregates (the M-tile IS one 128-row chunk)
// 128x128 tile, BK=32, 4 waves (2x2 of 64x64), 16x16x32 bf16 MFMA,
// global_load_lds w=16 with pre-swizzled source + swizzled ds_read (T2/rule21).
// ---------------------------------------------------------------------------
__global__ void __launch_bounds__(256) k_gemm(const unsigned short* __restrict__ xs,
                                              const unsigned short* __restrict__ wt,
                                              float2* __restrict__ cv,
                                              float2* __restrict__ agg) {
  __shared__ __align__(16) unsigned short As[128 * 32];
  __shared__ __align__(16) unsigned short Bs[128 * 32];
  __shared__ float aggC[2][2][2][16];   // [wr][wc][t][lane&15]
  __shared__ float aggV[2][2][2][16];

  const int tid  = threadIdx.x;
  const int lane = tid & 63;
  const int wave = tid >> 6;
  const int wr = wave >> 1, wc = wave & 1;
  const int bid = blockIdx.x;
  const int nb = bid & 7;        // 8 consecutive bids share the A panel
  const int mb = bid >> 3;       // 0..511  == b*64 + chunk
  const int m0 = mb * 128, n0 = nb * 128;

  f32x4 acc[4][4] = {};

  // staging: LDS is linear (tid*16 bytes per call-site); SOURCE is inverse-
  // swizzled so that LDS[r*64B + (c ^ ((r&3)<<4))] = global[r][c].
  const int trow = tid >> 2;
  const int tks  = 8 * ((tid & 3) ^ ((tid >> 2) & 3));   // swizzled k-chunk (shorts)
  const size_t aoff0 = (size_t)(m0 + trow) * 1024 + tks;
  const size_t aoff1 = aoff0 + (size_t)64 * 1024;
  const size_t boff0 = (size_t)(n0 + trow) * 1024 + tks;
  const size_t boff1 = boff0 + (size_t)64 * 1024;

  char* ldsA = (char*)As + wave * 1024;   // wave-uniform base (+ lane*16 by HW)
  char* ldsB = (char*)Bs + wave * 1024;

  // fragment read offset (shorts), swizzle applied: row = ..+(lane&15) so row&3 = lane&3
  const int ra = (lane & 15) * 32 + 8 * ((lane >> 4) ^ (lane & 3));

  for (int kt = 0; kt < 32; ++kt) {
    const int k0 = kt * 32;
    __syncthreads();
    gload16(xs + aoff0 + k0, ldsA);
    gload16(xs + aoff1 + k0, ldsA + 4096);
    gload16(wt + boff0 + k0, ldsB);
    gload16(wt + boff1 + k0, ldsB + 4096);
    __syncthreads();
    short8 af[4], bfr[4];
#pragma unroll
    for (int m = 0; m < 4; ++m)
      af[m] = *(const short8*)(As + (wr * 64 + 16 * m) * 32 + ra);
#pragma unroll
    for (int n = 0; n < 4; ++n)
      bfr[n] = *(const short8*)(Bs + (wc * 64 + 16 * n) * 32 + ra);
#pragma unroll
    for (int m = 0; m < 4; ++m)
#pragma unroll
      for (int n = 0; n < 4; ++n)
        acc[m][n] = __builtin_amdgcn_mfma_f32_16x16x32_bf16(af[m], bfr[n], acc[m][n], 0, 0, 0);
  }

  // ----- Epilogue: pointwise -> cv, + ordered chunk-aggregate -> agg -----
  // D layout: col = lane&15, row = (lane>>4)*4 + j  [measured m89]
  // local row r_l = wr*64 + 16m + 4q + j,  q = lane>>4
  const int q     = lane >> 4;
  const int rbase = m0 + wr * 64 + (q << 2);
  const int dbase = nb * 64 + wc * 32 + (lane & 15);

  float CW[2] = {1.f, 1.f};
  float VW[2] = {0.f, 0.f};

#pragma unroll
  for (int m = 0; m < 4; ++m) {
#pragma unroll
    for (int t = 0; t < 2; ++t) {
      float cseg = 1.f, vseg = 0.f;
#pragma unroll
      for (int j = 0; j < 4; ++j) {
        float hid = acc[m][2 * t][j];
        float gat = acc[m][2 * t + 1][j];
        float eg = __expf(gat);
        float c  = 1.f / (1.f + eg);     // sigmoid(-gate) = exp(-softplus(gate))
        float z  = 1.f - c;              // sigmoid(gate)
        float gv = (hid >= 0.f) ? (hid + 0.5f) : (1.f / (1.f + __expf(-hid)));
        float v  = z * gv;
        int R = rbase + 16 * m + j;
        int d = dbase + 16 * t;
        cv[(size_t)R * 512 + d] = make_float2(c, v);
        vseg = fmaf(c, vseg, v);         // ordered fold over j
        cseg *= c;
      }
      // ordered combine across q (lane-groups), q ascending = row order
      {
        float Cp = __shfl_xor(cseg, 16);
        float Vp = __shfl_xor(vseg, 16);
        if (q & 1) { vseg = fmaf(cseg, Vp, vseg); cseg = Cp * cseg; }
        else       { vseg = fmaf(Cp, vseg, Vp);   cseg = cseg * Cp; }
        Cp = __shfl_xor(cseg, 32);
        Vp = __shfl_xor(vseg, 32);
        if (q & 2) { vseg = fmaf(cseg, Vp, vseg); cseg = Cp * cseg; }
        else       { vseg = fmaf(Cp, vseg, Vp);   cseg = cseg * Cp; }
      }
      // fold 16-row segment into wave-half aggregate (m ascending = row order)
      VW[t] = fmaf(cseg, VW[t], vseg);
      CW[t] *= cseg;
    }
  }

  if (lane < 16) {
#pragma unroll
    for (int t = 0; t < 2; ++t) {
      aggC[wr][wc][t][lane] = CW[t];
      aggV[wr][wc][t][lane] = VW[t];
    }
  }
  __syncthreads();
  if (wr == 0 && lane < 16) {
#pragma unroll
    for (int t = 0; t < 2; ++t) {
      float C1 = aggC[1][wc][t][lane];
      float V1 = aggV[1][wc][t][lane];
      int d = nb * 64 + wc * 32 + t * 16 + lane;
      // rows 0..63 (this wave-pair's regs) then rows 64..127
      agg[(size_t)mb * 512 + d] = make_float2(CW[t] * C1, fmaf(C1, VW[t], V1));
    }
  }
}

// ---------------------------------------------------------------------------
// Scan kernel B: chain the 64 chunk aggregates per (b,d); h0 = g(prev_hidden)
// ---------------------------------------------------------------------------
__global__ void k_chain(const float* __restrict__ prev, const float2* __restrict__ agg,
                        float* __restrict__ hin) {
  const int b = blockIdx.x;
  const int d = threadIdx.x;  // 512 threads
  float p = prev[b * 512 + d];
  float h = (p >= 0.f) ? (p + 0.5f) : (1.f / (1.f + __expf(-p)));
  for (int k = 0; k < NC; ++k) {
    size_t idx = ((size_t)(b * NC + k)) * 512 + d;
    hin[idx] = h;
    float2 a = agg[idx];
    h = fmaf(a.x, h, a.y);
  }
}

// ---------------------------------------------------------------------------
// Scan kernel C: replay chunks with correct incoming h, write output
// 2 adjacent d per thread (float4 cv loads, float2 out stores)
// ---------------------------------------------------------------------------
__global__ void k_scan_out(const float2* __restrict__ cv, const float* __restrict__ hin,
                           float* __restrict__ out) {
  const int bid = blockIdx.x;       // 512 = 8 b * 64 chunks
  const int chunk = bid & 63;
  const int b = bid >> 6;
  const int d0 = threadIdx.x * 2;   // 256 threads cover 512 d
  float2 h2 = *(const float2*)(hin + ((size_t)(b * NC + chunk)) * 512 + d0);
  const size_t base = ((size_t)(b * Ss + chunk * CL)) * 512 + d0;
#pragma unroll 8
  for (int i = 0; i < CL; ++i) {
    float4 t = *(const float4*)(cv + base + (size_t)i * 512);
    h2.x = fmaf(t.x, h2.x, t.y);
    h2.y = fmaf(t.z, h2.y, t.w);
    *(float2*)(out + base + (size_t)i * 512) = h2;
  }
}

// ---------------------------------------------------------------------------
extern "C" void kernel_launch(void* const* d_in, const int* in_sizes, int n_in,
                              void* d_out, int out_size, void* d_ws, size_t ws_size,
                              hipStream_t stream) {
  if (ws_size < WS_NEED) return;  // need ~390 MiB scratch

  const float* x    = (const float*)d_in[0];
  const float* prev = (const float*)d_in[1];
  const float* W    = (const float*)d_in[2];
  float* out = (float*)d_out;
  char* ws = (char*)d_ws;

  float2*         cv  = (float2*)(ws + CV_OFF);
  unsigned short* xs  = (unsigned short*)(ws + XS_OFF);
  unsigned short* wt  = (unsigned short*)(ws + WT_OFF);
  float2*         agg = (float2*)(ws + AG_OFF);
  float*          hin = (float*)(ws + HIN_OFF);

  k_convert_x<<<dim3(4096), dim3(256), 0, stream>>>(x, xs);
  k_build_wt<<<dim3(512), dim3(256), 0, stream>>>(W, wt);
  k_gemm<<<dim3(4096), dim3(256), 0, stream>>>(xs, wt, cv, agg);
  k_chain<<<dim3(8), dim3(512), 0, stream>>>(prev, agg, hin);
  k_scan_out<<<dim3(512), dim3(256), 0, stream>>>(cv, hin, out);
}

// Round 4
// 478.981 us; speedup vs baseline: 1.4077x; 1.1298x over previous
//
#include <hip/hip_runtime.h>
#include <stdint.h>

// Problem constants (B=8, S=8192, D_IN=512, D=512)
#define Bb   8
#define Ss   8192
#define DIN  512
#define Dd   512
#define M_TOT (Bb * Ss)      // 65536 rows
#define NC   64              // chunks along S
#define CL   128             // chunk length (NC*CL == Ss) == GEMM M-tile

// ws layout (bytes)
static const size_t CV_OFF  = 0;                          // bf16x2 [65536][512] = 128 MiB
static const size_t XS_OFF  = 134217728ull;               // bf16 [65536][1024] = 128 MiB (hi|lo)
static const size_t WT_OFF  = XS_OFF + 134217728ull;      // bf16 [1024][1024]  = 2 MiB
static const size_t AG_OFF  = WT_OFF + 2097152ull;        // float2[512][512]   = 2 MiB
static const size_t HIN_OFF = AG_OFF + 2097152ull;        // float [8][64][512] = 1 MiB
static const size_t WS_NEED = HIN_OFF + 1048576ull;       // ~262 MiB total

typedef short  short8 __attribute__((ext_vector_type(8)));
typedef float  f32x4  __attribute__((ext_vector_type(4)));

__device__ __forceinline__ unsigned short bf16_rne(float f) {
  uint32_t u = __float_as_uint(f);
  u += 0x7fffu + ((u >> 16) & 1u);
  return (unsigned short)(u >> 16);
}
__device__ __forceinline__ float bf16f(unsigned short h) {
  return __uint_as_float(((uint32_t)h) << 16);
}

__device__ __forceinline__ void gload16(const unsigned short* g, void* l) {
  __builtin_amdgcn_global_load_lds(
      (const __attribute__((address_space(1))) uint32_t*)g,
      (__attribute__((address_space(3))) uint32_t*)l, 16, 0, 0);
}

// ---------------------------------------------------------------------------
// Pre-pass 1: x (f32) -> xs bf16 [row][0:512)=hi, [512:1024)=lo
// ---------------------------------------------------------------------------
__global__ void k_convert_x(const float* __restrict__ x, unsigned short* __restrict__ xs) {
  const size_t n4 = (size_t)M_TOT * DIN / 4;
  for (size_t i = (size_t)blockIdx.x * blockDim.x + threadIdx.x; i < n4;
       i += (size_t)gridDim.x * blockDim.x) {
    float4 v = ((const float4*)x)[i];
    size_t e = i * 4;
    size_t r = e >> 9;            // row (0..65535)
    int    k = (int)(e & 511);    // col in [0,512), multiple of 4
    float f[4] = {v.x, v.y, v.z, v.w};
    ushort4 hi, lo;
    unsigned short* hp = (unsigned short*)&hi;
    unsigned short* lp = (unsigned short*)&lo;
#pragma unroll
    for (int j = 0; j < 4; ++j) {
      unsigned short h = bf16_rne(f[j]);
      hp[j] = h;
      lp[j] = bf16_rne(f[j] - bf16f(h));
    }
    *(ushort4*)(xs + r * 1024 + k)       = hi;
    *(ushort4*)(xs + r * 1024 + 512 + k) = lo;
  }
}

// ---------------------------------------------------------------------------
// Pre-pass 2: build Wt bf16 [1024 n'][1024 k]  (B = [Wh | Wh], k dup at 512)
//   n' column interleave (16-granular): t = n'>>5, u = n'&31
//     u<16  -> hidden col  d = 16t + u;  u>=16 -> gate col d = 16t + (u-16)
// ---------------------------------------------------------------------------
__global__ void k_build_wt(const float* __restrict__ W, unsigned short* __restrict__ wt) {
  const int total = 1024 * 1024;
  for (int i = blockIdx.x * blockDim.x + threadIdx.x; i < total;
       i += gridDim.x * blockDim.x) {
    int n = i >> 10;
    int k = i & 1023;
    int t = n >> 5, u = n & 31;
    int j = 16 * t + (u & 15) + ((u & 16) ? 512 : 0);
    int ks = k & 511;
    wt[i] = bf16_rne(W[(size_t)ks * 1024 + j]);
  }
}

// ---------------------------------------------------------------------------
// GEMM: (65536 x 1024_eff) * (1024 x 1024) -> fused pointwise -> cv bf16x2
//       + fused per-chunk scan aggregates (M-tile IS one 128-row chunk)
// 128x128 tile, BK=32, 4 waves (2x2 of 64x64), 16x16x32 bf16 MFMA.
// LDS swizzle (rule 21): linear gload_lds dest; SOURCE chunk = s ^ ((r>>1)&3);
// READ slot = q ^ ((r>>1)&3) -> bank period covers all 8 slots 2x (free 2-way).
// XCD-aware mapping: 8 nb-blocks sharing an A-panel land on the SAME XCD.
// ---------------------------------------------------------------------------
__global__ void __launch_bounds__(256) k_gemm(const unsigned short* __restrict__ xs,
                                              const unsigned short* __restrict__ wt,
                                              uint32_t* __restrict__ cvu,
                                              float2* __restrict__ agg) {
  __shared__ __align__(16) unsigned short As[128 * 32];
  __shared__ __align__(16) unsigned short Bs[128 * 32];
  __shared__ float aggC[2][2][2][16];   // [wr][wc][t][lane&15]
  __shared__ float aggV[2][2][2][16];

  const int tid  = threadIdx.x;
  const int lane = tid & 63;
  const int wave = tid >> 6;
  const int wr = wave >> 1, wc = wave & 1;

  // XCD-aware tile mapping (round-robin bid%8 -> XCD assumed)
  const int bid = blockIdx.x;
  const int xcd = bid & 7;
  const int j8  = bid >> 3;              // 0..511, sequential per XCD
  const int mb  = xcd * 64 + (j8 >> 3);  // 64 mb's per XCD; 8 consecutive
  const int nb  = j8 & 7;                //   blocks per XCD share one A-panel
  const int m0 = mb * 128, n0 = nb * 128;

  f32x4 acc[4][4] = {};

  // staging: LDS linear (row = tid>>2, slot = tid&3); source chunk swizzled
  const int trow = tid >> 2;
  const int tks  = 8 * ((tid & 3) ^ ((tid >> 3) & 3));   // shorts
  const size_t aoff0 = (size_t)(m0 + trow) * 1024 + tks;
  const size_t aoff1 = aoff0 + (size_t)64 * 1024;
  const size_t boff0 = (size_t)(n0 + trow) * 1024 + tks;
  const size_t boff1 = boff0 + (size_t)64 * 1024;

  char* ldsA = (char*)As + wave * 1024;   // wave-uniform base (+ lane*16 by HW)
  char* ldsB = (char*)Bs + wave * 1024;

  // fragment read offset (shorts): row=(lane&15)+16*seg, slot=q^((row>>1)&3)
  const int ra = (lane & 15) * 32 + 8 * ((lane >> 4) ^ ((lane >> 1) & 3));

  for (int kt = 0; kt < 32; ++kt) {
    const int k0 = kt * 32;
    __syncthreads();
    gload16(xs + aoff0 + k0, ldsA);
    gload16(xs + aoff1 + k0, ldsA + 4096);
    gload16(wt + boff0 + k0, ldsB);
    gload16(wt + boff1 + k0, ldsB + 4096);
    __syncthreads();
    short8 af[4], bfr[4];
#pragma unroll
    for (int m = 0; m < 4; ++m)
      af[m] = *(const short8*)(As + (wr * 64 + 16 * m) * 32 + ra);
#pragma unroll
    for (int n = 0; n < 4; ++n)
      bfr[n] = *(const short8*)(Bs + (wc * 64 + 16 * n) * 32 + ra);
#pragma unroll
    for (int m = 0; m < 4; ++m)
#pragma unroll
      for (int n = 0; n < 4; ++n)
        acc[m][n] = __builtin_amdgcn_mfma_f32_16x16x32_bf16(af[m], bfr[n], acc[m][n], 0, 0, 0);
  }

  // ----- Epilogue: pointwise -> cv (bf16x2), + ordered chunk-aggregate -----
  // D layout: col = lane&15, row = (lane>>4)*4 + j  [measured m89]
  const int q     = lane >> 4;
  const int rbase = m0 + wr * 64 + (q << 2);
  const int dbase = nb * 64 + wc * 32 + (lane & 15);

  float CW[2] = {1.f, 1.f};
  float VW[2] = {0.f, 0.f};

#pragma unroll
  for (int m = 0; m < 4; ++m) {
#pragma unroll
    for (int t = 0; t < 2; ++t) {
      float cseg = 1.f, vseg = 0.f;
#pragma unroll
      for (int j = 0; j < 4; ++j) {
        float hid = acc[m][2 * t][j];
        float gat = acc[m][2 * t + 1][j];
        float eg = __expf(gat);
        float c  = 1.f / (1.f + eg);     // sigmoid(-gate) = exp(-softplus(gate))
        float z  = 1.f - c;              // sigmoid(gate)
        float gv = (hid >= 0.f) ? (hid + 0.5f) : (1.f / (1.f + __expf(-hid)));
        float v  = z * gv;
        int R = rbase + 16 * m + j;
        int d = dbase + 16 * t;
        cvu[(size_t)R * 512 + d] =
            (uint32_t)bf16_rne(c) | ((uint32_t)bf16_rne(v) << 16);
        vseg = fmaf(c, vseg, v);         // ordered fold over j (f32-exact path)
        cseg *= c;
      }
      // ordered combine across q (lane-groups), q ascending = row order
      {
        float Cp = __shfl_xor(cseg, 16);
        float Vp = __shfl_xor(vseg, 16);
        if (q & 1) { vseg = fmaf(cseg, Vp, vseg); cseg = Cp * cseg; }
        else       { vseg = fmaf(Cp, vseg, Vp);   cseg = cseg * Cp; }
        Cp = __shfl_xor(cseg, 32);
        Vp = __shfl_xor(vseg, 32);
        if (q & 2) { vseg = fmaf(cseg, Vp, vseg); cseg = Cp * cseg; }
        else       { vseg = fmaf(Cp, vseg, Vp);   cseg = cseg * Cp; }
      }
      VW[t] = fmaf(cseg, VW[t], vseg);   // fold 16-row segment, m ascending
      CW[t] *= cseg;
    }
  }

  if (lane < 16) {
#pragma unroll
    for (int t = 0; t < 2; ++t) {
      aggC[wr][wc][t][lane] = CW[t];
      aggV[wr][wc][t][lane] = VW[t];
    }
  }
  __syncthreads();
  if (wr == 0 && lane < 16) {
#pragma unroll
    for (int t = 0; t < 2; ++t) {
      float C1 = aggC[1][wc][t][lane];
      float V1 = aggV[1][wc][t][lane];
      int d = nb * 64 + wc * 32 + t * 16 + lane;
      agg[(size_t)mb * 512 + d] = make_float2(CW[t] * C1, fmaf(C1, VW[t], V1));
    }
  }
}

// ---------------------------------------------------------------------------
// Scan kernel B: chain 64 chunk aggregates per (b,d); h0 = g(prev_hidden).
// Full preload -> 64 independent (pipelined) loads instead of serial latency.
// ---------------------------------------------------------------------------
__global__ void k_chain(const float* __restrict__ prev, const float2* __restrict__ agg,
                        float* __restrict__ hin) {
  const int b = blockIdx.x >> 1;                       // 16 blocks
  const int d = (blockIdx.x & 1) * 256 + threadIdx.x;  // 256 threads
  float p = prev[b * 512 + d];
  float h = (p >= 0.f) ? (p + 0.5f) : (1.f / (1.f + __expf(-p)));
  float2 a[NC];
#pragma unroll
  for (int k = 0; k < NC; ++k)
    a[k] = agg[((size_t)(b * NC + k)) * 512 + d];
#pragma unroll
  for (int k = 0; k < NC; ++k) {
    hin[((size_t)(b * NC + k)) * 512 + d] = h;
    h = fmaf(a[k].x, h, a[k].y);
  }
}

// ---------------------------------------------------------------------------
// Scan kernel C: replay chunks with exact incoming h, write output (f32)
// cv is bf16x2 (uint per element); 2 adjacent d per thread (uint2 loads)
// ---------------------------------------------------------------------------
__global__ void k_scan_out(const uint32_t* __restrict__ cvu, const float* __restrict__ hin,
                           float* __restrict__ out) {
  const int bid = blockIdx.x;       // 512 = 8 b * 64 chunks
  const int chunk = bid & 63;
  const int b = bid >> 6;
  const int d0 = threadIdx.x * 2;   // 256 threads cover 512 d
  float2 h2 = *(const float2*)(hin + ((size_t)(b * NC + chunk)) * 512 + d0);
  const size_t base = ((size_t)(b * Ss + chunk * CL)) * 512 + d0;
#pragma unroll 8
  for (int i = 0; i < CL; ++i) {
    uint2 t = *(const uint2*)(cvu + base + (size_t)i * 512);
    float c0 = __uint_as_float(t.x << 16);
    float v0 = __uint_as_float(t.x & 0xFFFF0000u);
    float c1 = __uint_as_float(t.y << 16);
    float v1 = __uint_as_float(t.y & 0xFFFF0000u);
    h2.x = fmaf(c0, h2.x, v0);
    h2.y = fmaf(c1, h2.y, v1);
    *(float2*)(out + base + (size_t)i * 512) = h2;
  }
}

// ---------------------------------------------------------------------------
extern "C" void kernel_launch(void* const* d_in, const int* in_sizes, int n_in,
                              void* d_out, int out_size, void* d_ws, size_t ws_size,
                              hipStream_t stream) {
  if (ws_size < WS_NEED) return;  // need ~262 MiB scratch

  const float* x    = (const float*)d_in[0];
  const float* prev = (const float*)d_in[1];
  const float* W    = (const float*)d_in[2];
  float* out = (float*)d_out;
  char* ws = (char*)d_ws;

  uint32_t*       cvu = (uint32_t*)(ws + CV_OFF);
  unsigned short* xs  = (unsigned short*)(ws + XS_OFF);
  unsigned short* wt  = (unsigned short*)(ws + WT_OFF);
  float2*         agg = (float2*)(ws + AG_OFF);
  float*          hin = (float*)(ws + HIN_OFF);

  k_convert_x<<<dim3(4096), dim3(256), 0, stream>>>(x, xs);
  k_build_wt<<<dim3(512), dim3(256), 0, stream>>>(W, wt);
  k_gemm<<<dim3(4096), dim3(256), 0, stream>>>(xs, wt, cvu, agg);
  k_chain<<<dim3(16), dim3(256), 0, stream>>>(prev, agg, hin);
  k_scan_out<<<dim3(512), dim3(256), 0, stream>>>(cvu, hin, out);
}

// Round 5
// 377.133 us; speedup vs baseline: 1.7879x; 1.2701x over previous
//
#include <hip/hip_runtime.h>
#include <stdint.h>

// Problem constants (B=8, S=8192, D_IN=512, D=512)
#define Bb   8
#define Ss   8192
#define DIN  512
#define Dd   512
#define M_TOT (Bb * Ss)      // 65536 rows
#define NC   64              // chunks along S
#define CL   128             // chunk length (NC*CL == Ss) == GEMM M-tile

// ws layout (bytes)
static const size_t CV_OFF  = 0;                          // bf16x2 [65536][512] = 128 MiB
static const size_t XS_OFF  = 134217728ull;               // bf16 [65536][512]  =  64 MiB
static const size_t WT_OFF  = XS_OFF + 67108864ull;       // bf16 [1024][512]   =   1 MiB
static const size_t AG_OFF  = WT_OFF + 1048576ull;        // float2[512][512]   =   2 MiB
static const size_t HIN_OFF = AG_OFF + 2097152ull;        // float [8][64][512] =   1 MiB
static const size_t WS_NEED = HIN_OFF + 1048576ull;       // ~196 MiB total

typedef short  short8 __attribute__((ext_vector_type(8)));
typedef float  f32x4  __attribute__((ext_vector_type(4)));

__device__ __forceinline__ unsigned short bf16_rne(float f) {
  uint32_t u = __float_as_uint(f);
  u += 0x7fffu + ((u >> 16) & 1u);
  return (unsigned short)(u >> 16);
}

__device__ __forceinline__ void gload16(const unsigned short* g, void* l) {
  __builtin_amdgcn_global_load_lds(
      (const __attribute__((address_space(1))) uint32_t*)g,
      (__attribute__((address_space(3))) uint32_t*)l, 16, 0, 0);
}

// ---------------------------------------------------------------------------
// Pre-pass (merged): blocks [0,4096): x f32 -> xs bf16 [row][512]
//                    blocks [4096,4608): W -> wt bf16 [1024 n'][512 k]
//   n' interleave (16-granular): t = n'>>5, u = n'&31
//     u<16 -> hidden col d = 16t+u ; u>=16 -> gate col d = 16t+(u-16)
// ---------------------------------------------------------------------------
__global__ void k_prep(const float* __restrict__ x, const float* __restrict__ W,
                       unsigned short* __restrict__ xs, unsigned short* __restrict__ wt) {
  const int bx = blockIdx.x;
  if (bx < 4096) {
    const size_t n4 = (size_t)M_TOT * DIN / 4;     // 8M float4
    for (size_t i = (size_t)bx * 256 + threadIdx.x; i < n4; i += (size_t)4096 * 256) {
      float4 v = ((const float4*)x)[i];
      size_t e = i * 4;
      size_t r = e >> 9;
      int    k = (int)(e & 511);
      ushort4 hi;
      unsigned short* hp = (unsigned short*)&hi;
      hp[0] = bf16_rne(v.x); hp[1] = bf16_rne(v.y);
      hp[2] = bf16_rne(v.z); hp[3] = bf16_rne(v.w);
      *(ushort4*)(xs + r * 512 + k) = hi;
    }
  } else {
    const int t0 = (bx - 4096) * 256 + threadIdx.x;   // 131072 threads
    for (int i = t0; i < 1024 * 512; i += 131072) {
      int n = i >> 9;
      int k = i & 511;
      int t = n >> 5, u = n & 31;
      int j = 16 * t + (u & 15) + ((u & 16) ? 512 : 0);
      wt[i] = bf16_rne(W[(size_t)k * 1024 + j]);
    }
  }
}

// ---------------------------------------------------------------------------
// GEMM: (65536 x 512) * (512 x 1024) -> fused pointwise -> cv bf16x2
//       + fused per-chunk scan aggregates (M-tile IS one 128-row chunk)
// 128x128 tile, BK=32, 4 waves (2x2 of 64x64), 16x16x32 bf16 MFMA.
// 2-phase double-buffered: STAGE(next) issued before compute(cur); the single
// __syncthreads per step drains vmcnt (next tile ready) -> latency hidden.
// LDS swizzle (rule 21): linear gload_lds dest; SOURCE chunk = s^((r>>1)&3);
// READ slot = q^((r>>1)&3). XCD-aware mapping: A-panel sharers on same XCD.
// ---------------------------------------------------------------------------
__global__ void __launch_bounds__(256) k_gemm(const unsigned short* __restrict__ xs,
                                              const unsigned short* __restrict__ wt,
                                              uint32_t* __restrict__ cvu,
                                              float2* __restrict__ agg) {
  __shared__ __align__(16) unsigned short As[2][128 * 32];
  __shared__ __align__(16) unsigned short Bsh[2][128 * 32];
  __shared__ float aggC[2][2][2][16];   // [wr][wc][t][lane&15]
  __shared__ float aggV[2][2][2][16];

  const int tid  = threadIdx.x;
  const int lane = tid & 63;
  const int wave = tid >> 6;
  const int wr = wave >> 1, wc = wave & 1;

  // XCD-aware tile mapping (round-robin bid%8 -> XCD assumed)
  const int bid = blockIdx.x;
  const int xcd = bid & 7;
  const int j8  = bid >> 3;              // 0..511, sequential per XCD
  const int mb  = xcd * 64 + (j8 >> 3);  // 64 mb's per XCD; 8 consecutive
  const int nb  = j8 & 7;                //   blocks per XCD share one A-panel
  const int m0 = mb * 128, n0 = nb * 128;

  f32x4 acc[4][4] = {};

  // staging: LDS linear (row = tid>>2, slot = tid&3); source chunk swizzled
  const int trow = tid >> 2;
  const int tks  = 8 * ((tid & 3) ^ ((tid >> 3) & 3));   // shorts
  const size_t aoff0 = (size_t)(m0 + trow) * 512 + tks;
  const size_t aoff1 = aoff0 + (size_t)64 * 512;
  const size_t boff0 = (size_t)(n0 + trow) * 512 + tks;
  const size_t boff1 = boff0 + (size_t)64 * 512;

  // fragment read offset (shorts): row=(lane&15)+16*seg, slot=q^((row>>1)&3)
  const int ra = (lane & 15) * 32 + 8 * ((lane >> 4) ^ ((lane >> 1) & 3));

#define STAGE(bf, k0) { \
    char* la = (char*)As  + (bf) * 8192 + wave * 1024; \
    char* lb = (char*)Bsh + (bf) * 8192 + wave * 1024; \
    gload16(xs + aoff0 + (k0), la); \
    gload16(xs + aoff1 + (k0), la + 4096); \
    gload16(wt + boff0 + (k0), lb); \
    gload16(wt + boff1 + (k0), lb + 4096); }

#define COMPUTE(bf) { \
    const unsigned short* Ab = &As[bf][0]; \
    const unsigned short* Bb2 = &Bsh[bf][0]; \
    short8 af[4], bfr[4]; \
    _Pragma("unroll") for (int m = 0; m < 4; ++m) \
      af[m] = *(const short8*)(Ab + (wr * 64 + 16 * m) * 32 + ra); \
    _Pragma("unroll") for (int n = 0; n < 4; ++n) \
      bfr[n] = *(const short8*)(Bb2 + (wc * 64 + 16 * n) * 32 + ra); \
    _Pragma("unroll") for (int m = 0; m < 4; ++m) \
      _Pragma("unroll") for (int n = 0; n < 4; ++n) \
        acc[m][n] = __builtin_amdgcn_mfma_f32_16x16x32_bf16(af[m], bfr[n], acc[m][n], 0, 0, 0); }

  STAGE(0, 0);
  __syncthreads();
  int buf = 0;
  for (int kt = 0; kt < 15; ++kt) {
    STAGE(buf ^ 1, (kt + 1) * 32);   // issue next-tile loads FIRST
    COMPUTE(buf);                     // ds_read + MFMA hide the load latency
    __syncthreads();                  // implicit vmcnt(0): next tile ready
    buf ^= 1;
  }
  COMPUTE(buf);

  // ----- Epilogue: pointwise -> cv (bf16x2), + ordered chunk-aggregate -----
  // D layout: col = lane&15, row = (lane>>4)*4 + j  [measured m89]
  const int q     = lane >> 4;
  const int rbase = m0 + wr * 64 + (q << 2);
  const int dbase = nb * 64 + wc * 32 + (lane & 15);

  float CW[2] = {1.f, 1.f};
  float VW[2] = {0.f, 0.f};

#pragma unroll
  for (int m = 0; m < 4; ++m) {
#pragma unroll
    for (int t = 0; t < 2; ++t) {
      float cseg = 1.f, vseg = 0.f;
#pragma unroll
      for (int j = 0; j < 4; ++j) {
        float hid = acc[m][2 * t][j];
        float gat = acc[m][2 * t + 1][j];
        float eg = __expf(gat);
        float c  = 1.f / (1.f + eg);     // sigmoid(-gate) = exp(-softplus(gate))
        float z  = 1.f - c;              // sigmoid(gate)
        float gv = (hid >= 0.f) ? (hid + 0.5f) : (1.f / (1.f + __expf(-hid)));
        float v  = z * gv;
        int R = rbase + 16 * m + j;
        int d = dbase + 16 * t;
        cvu[(size_t)R * 512 + d] =
            (uint32_t)bf16_rne(c) | ((uint32_t)bf16_rne(v) << 16);
        vseg = fmaf(c, vseg, v);         // ordered fold over j (f32-exact path)
        cseg *= c;
      }
      // ordered combine across q (lane-groups), q ascending = row order
      {
        float Cp = __shfl_xor(cseg, 16);
        float Vp = __shfl_xor(vseg, 16);
        if (q & 1) { vseg = fmaf(cseg, Vp, vseg); cseg = Cp * cseg; }
        else       { vseg = fmaf(Cp, vseg, Vp);   cseg = cseg * Cp; }
        Cp = __shfl_xor(cseg, 32);
        Vp = __shfl_xor(vseg, 32);
        if (q & 2) { vseg = fmaf(cseg, Vp, vseg); cseg = Cp * cseg; }
        else       { vseg = fmaf(Cp, vseg, Vp);   cseg = cseg * Cp; }
      }
      VW[t] = fmaf(cseg, VW[t], vseg);   // fold 16-row segment, m ascending
      CW[t] *= cseg;
    }
  }

  if (lane < 16) {
#pragma unroll
    for (int t = 0; t < 2; ++t) {
      aggC[wr][wc][t][lane] = CW[t];
      aggV[wr][wc][t][lane] = VW[t];
    }
  }
  __syncthreads();
  if (wr == 0 && lane < 16) {
#pragma unroll
    for (int t = 0; t < 2; ++t) {
      float C1 = aggC[1][wc][t][lane];
      float V1 = aggV[1][wc][t][lane];
      int d = nb * 64 + wc * 32 + t * 16 + lane;
      agg[(size_t)mb * 512 + d] = make_float2(CW[t] * C1, fmaf(C1, VW[t], V1));
    }
  }
}

// ---------------------------------------------------------------------------
// Scan kernel B: chain 64 chunk aggregates per (b,d); h0 = g(prev_hidden).
// ---------------------------------------------------------------------------
__global__ void k_chain(const float* __restrict__ prev, const float2* __restrict__ agg,
                        float* __restrict__ hin) {
  const int b = blockIdx.x >> 1;                       // 16 blocks
  const int d = (blockIdx.x & 1) * 256 + threadIdx.x;  // 256 threads
  float p = prev[b * 512 + d];
  float h = (p >= 0.f) ? (p + 0.5f) : (1.f / (1.f + __expf(-p)));
  float2 a[NC];
#pragma unroll
  for (int k = 0; k < NC; ++k)
    a[k] = agg[((size_t)(b * NC + k)) * 512 + d];
#pragma unroll
  for (int k = 0; k < NC; ++k) {
    hin[((size_t)(b * NC + k)) * 512 + d] = h;
    h = fmaf(a[k].x, h, a[k].y);
  }
}

// ---------------------------------------------------------------------------
// Scan kernel C: replay chunks with exact incoming h, write output (f32)
// ---------------------------------------------------------------------------
__global__ void k_scan_out(const uint32_t* __restrict__ cvu, const float* __restrict__ hin,
                           float* __restrict__ out) {
  const int bid = blockIdx.x;       // 512 = 8 b * 64 chunks
  const int chunk = bid & 63;
  const int b = bid >> 6;
  const int d0 = threadIdx.x * 2;   // 256 threads cover 512 d
  float2 h2 = *(const float2*)(hin + ((size_t)(b * NC + chunk)) * 512 + d0);
  const size_t base = ((size_t)(b * Ss + chunk * CL)) * 512 + d0;
#pragma unroll 8
  for (int i = 0; i < CL; ++i) {
    uint2 t = *(const uint2*)(cvu + base + (size_t)i * 512);
    float c0 = __uint_as_float(t.x << 16);
    float v0 = __uint_as_float(t.x & 0xFFFF0000u);
    float c1 = __uint_as_float(t.y << 16);
    float v1 = __uint_as_float(t.y & 0xFFFF0000u);
    h2.x = fmaf(c0, h2.x, v0);
    h2.y = fmaf(c1, h2.y, v1);
    *(float2*)(out + base + (size_t)i * 512) = h2;
  }
}

// ---------------------------------------------------------------------------
extern "C" void kernel_launch(void* const* d_in, const int* in_sizes, int n_in,
                              void* d_out, int out_size, void* d_ws, size_t ws_size,
                              hipStream_t stream) {
  if (ws_size < WS_NEED) return;  // need ~196 MiB scratch

  const float* x    = (const float*)d_in[0];
  const float* prev = (const float*)d_in[1];
  const float* W    = (const float*)d_in[2];
  float* out = (float*)d_out;
  char* ws = (char*)d_ws;

  uint32_t*       cvu = (uint32_t*)(ws + CV_OFF);
  unsigned short* xs  = (unsigned short*)(ws + XS_OFF);
  unsigned short* wt  = (unsigned short*)(ws + WT_OFF);
  float2*         agg = (float2*)(ws + AG_OFF);
  float*          hin = (float*)(ws + HIN_OFF);

  k_prep<<<dim3(4608), dim3(256), 0, stream>>>(x, W, xs, wt);
  k_gemm<<<dim3(4096), dim3(256), 0, stream>>>(xs, wt, cvu, agg);
  k_chain<<<dim3(16), dim3(256), 0, stream>>>(prev, agg, hin);
  k_scan_out<<<dim3(512), dim3(256), 0, stream>>>(cvu, hin, out);
}